// Round 7
// baseline (391.256 us; speedup 1.0000x reference)
//
#include <hip/hip_runtime.h>
#include <hip/hip_bf16.h>
#include <math.h>

#define BATCH 128
#define NEUR 54
#define DT 4
#define STEPS 30
#define PDIM 75             // pooled spatial dim
#define K (PDIM * PDIM)     // 5625
#define QK 1408             // quarter-K padded to 22*64; q=3 covers only 1401
#define NQ 4
#define TOT (BATCH * NEUR)  // 6912
#define RTPB 1024

// ---------------- Kernel 1 (fused): pool quarter-row into LDS, then partial FC -----
// R6-verified best form (329.5 us): round-0 fused kernel, bitwise-identical xf_part.
// grid = 512 blocks: block = (batch b, quarter q). 1024 threads, 2 blocks/CU so the
// HBM-bound pool phase of one block overlaps the L2/VALU-bound FC phase of its
// co-resident neighbor. R5's split variant measured net -11 us worse.
__global__ __launch_bounds__(1024) void poolfc_kernel(const float* __restrict__ x,
                                                      const float* __restrict__ fc_w,
                                                      float* __restrict__ xf_part) {
    __shared__ float xps[QK];
    int blk = blockIdx.x;
    int b = blk >> 2;
    int q = blk & 3;
    int tid = threadIdx.x;
    int kbase = q * QK;
    int cnt = (q == 3) ? (K - 3 * QK) : QK;  // 1401 or 1408
    const float* xrow = x + (size_t)b * 360000;

    // ---- pool phase: avg_pool2d(x,8) for this quarter -> LDS (tail zeroed) ----
    for (int w = tid; w < QK; w += 1024) {
        float s = 0.f;
        if (w < cnt) {
            int gw = kbase + w;
            int i = gw / PDIM;
            int j = gw - i * PDIM;
            const float* base = xrow + (size_t)(i * 8) * 600 + j * 8;
#pragma unroll
            for (int r = 0; r < 8; r++) {
                const float4* p4 = (const float4*)(base + r * 600);
                float4 a = p4[0];
                float4 c = p4[1];
                s += a.x + a.y + a.z + a.w + c.x + c.y + c.z + c.w;
            }
            s *= (1.0f / 64.0f);
        }
        xps[w] = s;
    }
    __syncthreads();

    // ---- FC phase: wave w -> neurons 4w..4w+3, k on lanes (coalesced fc_w reads) ----
    int wid = tid >> 6, lane = tid & 63;
    int nb = wid * 4;  // waves 0..13 active, 14/15 idle
    if (nb < NEUR) {
        int v1 = (nb + 1 < NEUR), v2 = (nb + 2 < NEUR), v3 = (nb + 3 < NEUR);
        int n1 = v1 ? nb + 1 : nb;
        int n2 = v2 ? nb + 2 : nb;
        int n3 = v3 ? nb + 3 : nb;
        const float* p0 = fc_w + (size_t)nb * K + kbase;
        const float* p1 = fc_w + (size_t)n1 * K + kbase;
        const float* p2 = fc_w + (size_t)n2 * K + kbase;
        const float* p3 = fc_w + (size_t)n3 * K + kbase;
        float a0 = 0.f, a1 = 0.f, a2 = 0.f, a3 = 0.f;
        int full = (cnt == QK) ? (QK / 64) : (QK / 64 - 1);  // unguarded chunks
        for (int c = 0; c < full; c++) {
            int kk = c * 64 + lane;
            float xv = xps[kk];
            a0 += xv * p0[kk];
            a1 += xv * p1[kk];
            a2 += xv * p2[kk];
            a3 += xv * p3[kk];
        }
        if (cnt != QK) {  // guarded tail chunk (q==3 only)
            int kk = (QK / 64 - 1) * 64 + lane;
            if (kk < cnt) {
                float xv = xps[kk];
                a0 += xv * p0[kk];
                a1 += xv * p1[kk];
                a2 += xv * p2[kk];
                a3 += xv * p3[kk];
            }
        }
#pragma unroll
        for (int off = 32; off > 0; off >>= 1) {
            a0 += __shfl_xor(a0, off, 64);
            a1 += __shfl_xor(a1, off, 64);
            a2 += __shfl_xor(a2, off, 64);
            a3 += __shfl_xor(a3, off, 64);
        }
        if (lane == 0) {
            float* dst = xf_part + (size_t)q * (BATCH * 64) + b * 64 + nb;
            dst[0] = a0;
            if (v1) dst[1] = a1;
            if (v2) dst[2] = a2;
            if (v3) dst[3] = a3;
        }
    }
}

// ---------------- Kernel 2: 30-step GLM recurrence, single block --------------------
// 8 threads per batch (8*128 = 1024), <=7 neurons/thread. Register-critical at the
// 128-VGPR cap (R1: +35 VGPRs of state -> spill, +14 us). R7 changes, both
// register-flat issue-slot cuts (~174 -> ~127 slots/step):
//  (a) hterm folded into the lateral dot:  cur = xf + btl - dot(hist, lw - hw);
//      btl's needed sum(dot(hist,lw)) recovered via per-thread colsum[d] (+4 VGPRs,
//      maintained incrementally from spikes). lwmh REPLACES lw (same 28 VGPRs).
//  (b) 4-step unroll with static hist rotation: sp written into the vacated phys
//      slot (compile-time index (R+d)&3) -> no shift movs, red[s&1] static.
//      Adds NO live state, unlike R1's unroll. 30 = 4*7 + 2-step tail.
__global__ __launch_bounds__(RTPB) void recurrence_kernel(const float* __restrict__ xf_part,
                                                          const float* __restrict__ fc_b,
                                                          const float* __restrict__ l_weight,
                                                          const float* __restrict__ h_weight,
                                                          float* __restrict__ out) {
    __shared__ float red[2][16];

    int tid = threadIdx.x;
    int b = tid >> 3;
    int sub = tid & 7;
    int n0 = sub * 7;
    int cntn = NEUR - n0; if (cntn > 7) cntn = 7; if (cntn < 0) cntn = 0;  // sub=7 -> 5

    float hw0 = h_weight[0], hw1 = h_weight[1], hw2 = h_weight[2], hw3 = h_weight[3];

    float hist[7][DT];   // physical slots; logical lag d at phys (R+d)&3
    float lwmh[7][DT];   // lw - hw  (replaces lw; same register count)
    float colsum[DT];    // per-thread sum_j hist[j][.] (physical indexing)
    float xfv[7], cnt[7];

#pragma unroll
    for (int j = 0; j < 7; j++) {
        cnt[j] = 0.f;
#pragma unroll
        for (int d = 0; d < DT; d++) hist[j][d] = 0.f;
        if (j < cntn) {
            int n = n0 + j;
            xfv[j] = xf_part[b * 64 + n] + xf_part[BATCH * 64 + b * 64 + n] +
                     xf_part[2 * BATCH * 64 + b * 64 + n] +
                     xf_part[3 * BATCH * 64 + b * 64 + n] + fc_b[n];
            lwmh[j][0] = l_weight[n * DT + 0] - hw0;
            lwmh[j][1] = l_weight[n * DT + 1] - hw1;
            lwmh[j][2] = l_weight[n * DT + 2] - hw2;
            lwmh[j][3] = l_weight[n * DT + 3] - hw3;
        } else {
            xfv[j] = 0.f;
#pragma unroll
            for (int d = 0; d < DT; d++) lwmh[j][d] = 0.f;
        }
    }
#pragma unroll
    for (int d = 0; d < DT; d++) colsum[d] = 0.f;

    int wid = tid >> 6;  // 16 waves
    int lane = tid & 63;

    // One step at static rotation R (R = step mod 4). Logical lag d lives at
    // phys slot (R+d)&3; spike overwrites phys slot R&3 (the vacated oldest).
    // btl = sum_j dot(hist,lwmh) + dot(colsum,hw)  ==  sum_j dot(hist,lw).
    // cur = xfv - dot2[j] + btl  ==  xfv + (btl - hsum[j]) + hterm[j].
#define GLM_STEP(R)                                                                       \
    do {                                                                                  \
        float dot2[7];                                                                    \
        float btl = 0.f;                                                                  \
        _Pragma("unroll") for (int j = 0; j < 7; j++) {                                   \
            dot2[j] = hist[j][(R) & 3] * lwmh[j][0] + hist[j][((R) + 1) & 3] * lwmh[j][1] \
                    + hist[j][((R) + 2) & 3] * lwmh[j][2]                                 \
                    + hist[j][((R) + 3) & 3] * lwmh[j][3];                                \
            btl += dot2[j];                                                               \
        }                                                                                 \
        btl += colsum[(R) & 3] * hw0 + colsum[((R) + 1) & 3] * hw1                        \
             + colsum[((R) + 2) & 3] * hw2 + colsum[((R) + 3) & 3] * hw3;                 \
        _Pragma("unroll") for (int off = 4; off > 0; off >>= 1)                           \
            btl += __shfl_xor(btl, off, 8);                                               \
        float rate[7];                                                                    \
        float lsum = 0.f;                                                                 \
        _Pragma("unroll") for (int j = 0; j < 7; j++) {                                   \
            if (j < cntn) {                                                               \
                rate[j] = __expf((xfv[j] - dot2[j]) + btl);                               \
                lsum += rate[j];                                                          \
            }                                                                             \
        }                                                                                 \
        _Pragma("unroll") for (int off = 32; off > 0; off >>= 1)                          \
            lsum += __shfl_xor(lsum, off, 64);                                            \
        if (lane == 0) red[(R) & 1][wid] = lsum;                                          \
        __syncthreads();                                                                  \
        const float4* r4 = (const float4*)red[(R) & 1];                                   \
        float4 q0 = r4[0], q1 = r4[1], q2 = r4[2], q3 = r4[3];                            \
        float tsum = ((q0.x + q0.y) + (q0.z + q0.w)) + ((q1.x + q1.y) + (q1.z + q1.w)) +  \
                     ((q2.x + q2.y) + (q2.z + q2.w)) + ((q3.x + q3.y) + (q3.z + q3.w));   \
        float thr = tsum * (1.0f / (float)TOT);                                           \
        float spsum = 0.f;                                                                \
        _Pragma("unroll") for (int j = 0; j < 7; j++) {                                   \
            if (j < cntn) {                                                               \
                float sp = (rate[j] > thr) ? 1.0f : 0.0f;                                 \
                cnt[j] += sp;                                                             \
                hist[j][(R) & 3] = sp;                                                    \
                spsum += sp;                                                              \
            }                                                                             \
        }                                                                                 \
        colsum[(R) & 3] = spsum;                                                          \
        /* next step writes red[(R+1)&1] — other buffer, no second barrier needed */      \
    } while (0)

    for (int sb = 0; sb < 28; sb += 4) {  // 7 groups of 4
        GLM_STEP(0);
        GLM_STEP(1);
        GLM_STEP(2);
        GLM_STEP(3);
    }
    GLM_STEP(0);  // steps 28, 29
    GLM_STEP(1);
#undef GLM_STEP

#pragma unroll
    for (int j = 0; j < 7; j++) {
        if (j < cntn) {
            float c = cnt[j];
            out[b * NEUR + n0 + j] = c + log1pf(expf(-c));  // cold path: keep precise
        }
    }
}

extern "C" void kernel_launch(void* const* d_in, const int* in_sizes, int n_in,
                              void* d_out, int out_size, void* d_ws, size_t ws_size,
                              hipStream_t stream) {
    const float* x = (const float*)d_in[0];
    const float* l_weight = (const float*)d_in[1];
    const float* h_weight = (const float*)d_in[2];
    const float* fc_w = (const float*)d_in[3];
    const float* fc_b = (const float*)d_in[4];
    float* out = (float*)d_out;

    float* xf_part = (float*)d_ws;  // [4][128][64] = 131,072 B

    poolfc_kernel<<<BATCH * NQ, 1024, 0, stream>>>(x, fc_w, xf_part);
    recurrence_kernel<<<1, RTPB, 0, stream>>>(xf_part, fc_b, l_weight, h_weight, out);
}

// Round 8
// 331.015 us; speedup vs baseline: 1.1820x; 1.1820x over previous
//
#include <hip/hip_runtime.h>
#include <hip/hip_bf16.h>
#include <math.h>

#define BATCH 128
#define NEUR 54
#define DT 4
#define STEPS 30
#define PDIM 75             // pooled spatial dim
#define K (PDIM * PDIM)     // 5625
#define QK 1408             // quarter-K padded to 22*64; q=3 covers only 1401
#define NQ 4
#define TOT (BATCH * NEUR)  // 6912
#define RTPB 1024

// ---------------- Kernel 1 (fused): pool quarter-row into LDS, then partial FC -----
// R6-verified best form: round-0 fused kernel, bitwise-identical xf_part.
// grid = 512 blocks: block = (batch b, quarter q). 1024 threads, 2 blocks/CU so the
// HBM-bound pool phase of one block overlaps the L2/VALU-bound FC phase of its
// co-resident neighbor. (R5 split variant measured net -11 us.)
__global__ __launch_bounds__(1024) void poolfc_kernel(const float* __restrict__ x,
                                                      const float* __restrict__ fc_w,
                                                      float* __restrict__ xf_part) {
    __shared__ float xps[QK];
    int blk = blockIdx.x;
    int b = blk >> 2;
    int q = blk & 3;
    int tid = threadIdx.x;
    int kbase = q * QK;
    int cnt = (q == 3) ? (K - 3 * QK) : QK;  // 1401 or 1408
    const float* xrow = x + (size_t)b * 360000;

    // ---- pool phase: avg_pool2d(x,8) for this quarter -> LDS (tail zeroed) ----
    for (int w = tid; w < QK; w += 1024) {
        float s = 0.f;
        if (w < cnt) {
            int gw = kbase + w;
            int i = gw / PDIM;
            int j = gw - i * PDIM;
            const float* base = xrow + (size_t)(i * 8) * 600 + j * 8;
#pragma unroll
            for (int r = 0; r < 8; r++) {
                const float4* p4 = (const float4*)(base + r * 600);
                float4 a = p4[0];
                float4 c = p4[1];
                s += a.x + a.y + a.z + a.w + c.x + c.y + c.z + c.w;
            }
            s *= (1.0f / 64.0f);
        }
        xps[w] = s;
    }
    __syncthreads();

    // ---- FC phase: wave w -> neurons 4w..4w+3, k on lanes (coalesced fc_w reads) ----
    int wid = tid >> 6, lane = tid & 63;
    int nb = wid * 4;  // waves 0..13 active, 14/15 idle
    if (nb < NEUR) {
        int v1 = (nb + 1 < NEUR), v2 = (nb + 2 < NEUR), v3 = (nb + 3 < NEUR);
        int n1 = v1 ? nb + 1 : nb;
        int n2 = v2 ? nb + 2 : nb;
        int n3 = v3 ? nb + 3 : nb;
        const float* p0 = fc_w + (size_t)nb * K + kbase;
        const float* p1 = fc_w + (size_t)n1 * K + kbase;
        const float* p2 = fc_w + (size_t)n2 * K + kbase;
        const float* p3 = fc_w + (size_t)n3 * K + kbase;
        float a0 = 0.f, a1 = 0.f, a2 = 0.f, a3 = 0.f;
        int full = (cnt == QK) ? (QK / 64) : (QK / 64 - 1);  // unguarded chunks
        for (int c = 0; c < full; c++) {
            int kk = c * 64 + lane;
            float xv = xps[kk];
            a0 += xv * p0[kk];
            a1 += xv * p1[kk];
            a2 += xv * p2[kk];
            a3 += xv * p3[kk];
        }
        if (cnt != QK) {  // guarded tail chunk (q==3 only)
            int kk = (QK / 64 - 1) * 64 + lane;
            if (kk < cnt) {
                float xv = xps[kk];
                a0 += xv * p0[kk];
                a1 += xv * p1[kk];
                a2 += xv * p2[kk];
                a3 += xv * p3[kk];
            }
        }
#pragma unroll
        for (int off = 32; off > 0; off >>= 1) {
            a0 += __shfl_xor(a0, off, 64);
            a1 += __shfl_xor(a1, off, 64);
            a2 += __shfl_xor(a2, off, 64);
            a3 += __shfl_xor(a3, off, 64);
        }
        if (lane == 0) {
            float* dst = xf_part + (size_t)q * (BATCH * 64) + b * 64 + nb;
            dst[0] = a0;
            if (v1) dst[1] = a1;
            if (v2) dst[2] = a2;
            if (v3) dst[3] = a3;
        }
    }
}

// ---------------- Kernel 2: 30-step GLM recurrence, single block --------------------
// R6 code with ONE change: __launch_bounds__(1024, 4).
// R7's counters exposed the mechanism: bare launch_bounds(1024) makes the allocator
// target 2 blocks/CU (8 waves/SIMD -> 64-VGPR budget); our grid is ONE block, so the
// ~80-110 live floats spill to scratch for occupancy that can never exist (R7:
// VGPR_Count=64, WRITE_SIZE 211KB vs 27KB output, CU 72% stalled, 128 us).
// Pinning 4 waves/EU = 1 block/CU raises the budget to 128 VGPRs -> no spill.
__global__ __launch_bounds__(RTPB, 4) void recurrence_kernel(const float* __restrict__ xf_part,
                                                             const float* __restrict__ fc_b,
                                                             const float* __restrict__ l_weight,
                                                             const float* __restrict__ h_weight,
                                                             float* __restrict__ out) {
    __shared__ float red[2][16];

    int tid = threadIdx.x;
    int b = tid >> 3;
    int sub = tid & 7;
    int n0 = sub * 7;
    int cntn = NEUR - n0; if (cntn > 7) cntn = 7; if (cntn < 0) cntn = 0;  // sub=7 -> 5

    float hw0 = h_weight[0], hw1 = h_weight[1], hw2 = h_weight[2], hw3 = h_weight[3];

    float hist[7][DT];
    float lw[7][DT];
    float xfv[7], cnt[7], rate[7];

#pragma unroll
    for (int j = 0; j < 7; j++) {
        cnt[j] = 0.f;
#pragma unroll
        for (int d = 0; d < DT; d++) hist[j][d] = 0.f;
        if (j < cntn) {
            int n = n0 + j;
            xfv[j] = xf_part[b * 64 + n] + xf_part[BATCH * 64 + b * 64 + n] +
                     xf_part[2 * BATCH * 64 + b * 64 + n] +
                     xf_part[3 * BATCH * 64 + b * 64 + n] + fc_b[n];
#pragma unroll
            for (int d = 0; d < DT; d++) lw[j][d] = l_weight[n * DT + d];
        } else {
            xfv[j] = 0.f;
#pragma unroll
            for (int d = 0; d < DT; d++) lw[j][d] = 0.f;
        }
    }

    int wid = tid >> 6;  // 16 waves
    int lane = tid & 63;

    for (int s = 0; s < STEPS; s++) {
        float hsum[7];
        float btl = 0.f;
#pragma unroll
        for (int j = 0; j < 7; j++) {
            hsum[j] = hist[j][0] * lw[j][0] + hist[j][1] * lw[j][1] +
                      hist[j][2] * lw[j][2] + hist[j][3] * lw[j][3];
            btl += hsum[j];
        }
#pragma unroll
        for (int off = 4; off > 0; off >>= 1) btl += __shfl_xor(btl, off, 8);
        float lsum = 0.f;
#pragma unroll
        for (int j = 0; j < 7; j++) {
            if (j < cntn) {
                float hterm = hist[j][0] * hw0 + hist[j][1] * hw1 +
                              hist[j][2] * hw2 + hist[j][3] * hw3;
                float cur = xfv[j] + (btl - hsum[j]) + hterm;
                rate[j] = __expf(cur);
                lsum += rate[j];
            }
        }
#pragma unroll
        for (int off = 32; off > 0; off >>= 1) lsum += __shfl_xor(lsum, off, 64);
        if (lane == 0) red[s & 1][wid] = lsum;
        __syncthreads();
        const float4* r4 = (const float4*)red[s & 1];
        float4 q0 = r4[0], q1 = r4[1], q2 = r4[2], q3 = r4[3];
        float tsum = ((q0.x + q0.y) + (q0.z + q0.w)) + ((q1.x + q1.y) + (q1.z + q1.w)) +
                     ((q2.x + q2.y) + (q2.z + q2.w)) + ((q3.x + q3.y) + (q3.z + q3.w));
        float thr = tsum * (1.0f / (float)TOT);
#pragma unroll
        for (int j = 0; j < 7; j++) {
            if (j < cntn) {
                float sp = (rate[j] > thr) ? 1.0f : 0.0f;
                cnt[j] += sp;
                hist[j][0] = hist[j][1];
                hist[j][1] = hist[j][2];
                hist[j][2] = hist[j][3];
                hist[j][3] = sp;
            }
        }
        // next step writes red[(s+1)&1] — different buffer, no second barrier needed
    }

#pragma unroll
    for (int j = 0; j < 7; j++) {
        if (j < cntn) {
            float c = cnt[j];
            out[b * NEUR + n0 + j] = c + log1pf(expf(-c));  // cold path: keep precise
        }
    }
}

extern "C" void kernel_launch(void* const* d_in, const int* in_sizes, int n_in,
                              void* d_out, int out_size, void* d_ws, size_t ws_size,
                              hipStream_t stream) {
    const float* x = (const float*)d_in[0];
    const float* l_weight = (const float*)d_in[1];
    const float* h_weight = (const float*)d_in[2];
    const float* fc_w = (const float*)d_in[3];
    const float* fc_b = (const float*)d_in[4];
    float* out = (float*)d_out;

    float* xf_part = (float*)d_ws;  // [4][128][64] = 131,072 B

    poolfc_kernel<<<BATCH * NQ, 1024, 0, stream>>>(x, fc_w, xf_part);
    recurrence_kernel<<<1, RTPB, 0, stream>>>(xf_part, fc_b, l_weight, h_weight, out);
}

// Round 9
// 317.950 us; speedup vs baseline: 1.2306x; 1.0411x over previous
//
#include <hip/hip_runtime.h>
#include <hip/hip_bf16.h>
#include <math.h>

#define BATCH 128
#define NEUR 54
#define DT 4
#define STEPS 30
#define PDIM 75             // pooled spatial dim
#define K (PDIM * PDIM)     // 5625
#define QK 1408             // quarter-K padded to 22*64; q=3 covers only 1401
#define NQ 4
#define TOT (BATCH * NEUR)  // 6912
#define RTPB 1024

// ---------------- Kernel 1 (fused): pool quarter-row into LDS, then partial FC -----
// R6-verified best form: round-0 fused kernel, bitwise-identical xf_part.
// grid = 512 blocks: block = (batch b, quarter q). 1024 threads, 2 blocks/CU so the
// HBM-bound pool phase of one block overlaps the L2/VALU-bound FC phase of its
// co-resident neighbor. (R5 split variant measured net -11 us.)
__global__ __launch_bounds__(1024) void poolfc_kernel(const float* __restrict__ x,
                                                      const float* __restrict__ fc_w,
                                                      float* __restrict__ xf_part) {
    __shared__ float xps[QK];
    int blk = blockIdx.x;
    int b = blk >> 2;
    int q = blk & 3;
    int tid = threadIdx.x;
    int kbase = q * QK;
    int cnt = (q == 3) ? (K - 3 * QK) : QK;  // 1401 or 1408
    const float* xrow = x + (size_t)b * 360000;

    // ---- pool phase: avg_pool2d(x,8) for this quarter -> LDS (tail zeroed) ----
    for (int w = tid; w < QK; w += 1024) {
        float s = 0.f;
        if (w < cnt) {
            int gw = kbase + w;
            int i = gw / PDIM;
            int j = gw - i * PDIM;
            const float* base = xrow + (size_t)(i * 8) * 600 + j * 8;
#pragma unroll
            for (int r = 0; r < 8; r++) {
                const float4* p4 = (const float4*)(base + r * 600);
                float4 a = p4[0];
                float4 c = p4[1];
                s += a.x + a.y + a.z + a.w + c.x + c.y + c.z + c.w;
            }
            s *= (1.0f / 64.0f);
        }
        xps[w] = s;
    }
    __syncthreads();

    // ---- FC phase: wave w -> neurons 4w..4w+3, k on lanes (coalesced fc_w reads) ----
    int wid = tid >> 6, lane = tid & 63;
    int nb = wid * 4;  // waves 0..13 active, 14/15 idle
    if (nb < NEUR) {
        int v1 = (nb + 1 < NEUR), v2 = (nb + 2 < NEUR), v3 = (nb + 3 < NEUR);
        int n1 = v1 ? nb + 1 : nb;
        int n2 = v2 ? nb + 2 : nb;
        int n3 = v3 ? nb + 3 : nb;
        const float* p0 = fc_w + (size_t)nb * K + kbase;
        const float* p1 = fc_w + (size_t)n1 * K + kbase;
        const float* p2 = fc_w + (size_t)n2 * K + kbase;
        const float* p3 = fc_w + (size_t)n3 * K + kbase;
        float a0 = 0.f, a1 = 0.f, a2 = 0.f, a3 = 0.f;
        int full = (cnt == QK) ? (QK / 64) : (QK / 64 - 1);  // unguarded chunks
        for (int c = 0; c < full; c++) {
            int kk = c * 64 + lane;
            float xv = xps[kk];
            a0 += xv * p0[kk];
            a1 += xv * p1[kk];
            a2 += xv * p2[kk];
            a3 += xv * p3[kk];
        }
        if (cnt != QK) {  // guarded tail chunk (q==3 only)
            int kk = (QK / 64 - 1) * 64 + lane;
            if (kk < cnt) {
                float xv = xps[kk];
                a0 += xv * p0[kk];
                a1 += xv * p1[kk];
                a2 += xv * p2[kk];
                a3 += xv * p3[kk];
            }
        }
#pragma unroll
        for (int off = 32; off > 0; off >>= 1) {
            a0 += __shfl_xor(a0, off, 64);
            a1 += __shfl_xor(a1, off, 64);
            a2 += __shfl_xor(a2, off, 64);
            a3 += __shfl_xor(a3, off, 64);
        }
        if (lane == 0) {
            float* dst = xf_part + (size_t)q * (BATCH * 64) + b * 64 + nb;
            dst[0] = a0;
            if (v1) dst[1] = a1;
            if (v2) dst[2] = a2;
            if (v3) dst[3] = a3;
        }
    }
}

// ---------------- Kernel 2: 30-step GLM recurrence, single block --------------------
// R9: bitmask history + LDS lookup tables. Evidence chain: R7 showed the allocator
// pins this kernel at 64 VGPRs (2-blocks/CU heuristic) and spills; R8 showed the
// launch_bounds 2nd arg cannot raise the allocation; the __expf calibration (~11
// cyc per removed slot, 5x issue cost) fingerprints spill stalls in the hot loop.
// Fix: shrink live state below 64 instead of fighting the allocator.
//   hist[j][d] in {0,1}  ->  4-bit int hb[j]; dot(hist,lw) and dot(hist,hw) become
//   16-entry LDS tables g_tab[n][m], ht_tab[m]. Since h*w is exactly w or +0.0 and
//   x+0.0 == x, table entries built as ((a0+a1)+a2)+a3 are BIT-IDENTICAL to the
//   reference dots, and cur = (xfv + (btl-g)) + ht reproduces R6's rounding exactly.
// Steady live state: hb(7 int) + xfv(7) + cnt(7) + transients ~= 25 regs. No spill,
// no per-step shift movs (hb = (hb>>1)|spikebit).
__global__ __launch_bounds__(RTPB) void recurrence_kernel(const float* __restrict__ xf_part,
                                                          const float* __restrict__ fc_b,
                                                          const float* __restrict__ l_weight,
                                                          const float* __restrict__ h_weight,
                                                          float* __restrict__ out) {
    __shared__ float g_tab[NEUR * 16];  // g_tab[n*16+m] = sum_{d: bit d of m} lw[n][d]
    __shared__ float ht_tab[16];        // ht_tab[m]    = sum_{d: bit d of m} hw[d]
    __shared__ float red[2][16];

    int tid = threadIdx.x;
    int b = tid >> 3;
    int sub = tid & 7;
    int n0 = sub * 7;
    int cntn = NEUR - n0; if (cntn > 7) cntn = 7; if (cntn < 0) cntn = 0;  // sub=7 -> 5

    float hw0 = h_weight[0], hw1 = h_weight[1], hw2 = h_weight[2], hw3 = h_weight[3];

    // ---- build lookup tables (exact masked partial sums, sequential order) ----
    if (tid < NEUR * 16) {
        int n = tid >> 4, m = tid & 15;
        float l0 = l_weight[n * DT + 0];
        float l1 = l_weight[n * DT + 1];
        float l2 = l_weight[n * DT + 2];
        float l3 = l_weight[n * DT + 3];
        float a0 = (m & 1) ? l0 : 0.0f;
        float a1 = (m & 2) ? l1 : 0.0f;
        float a2 = (m & 4) ? l2 : 0.0f;
        float a3 = (m & 8) ? l3 : 0.0f;
        g_tab[tid] = ((a0 + a1) + a2) + a3;  // == h0*l0 + h1*l1 + h2*l2 + h3*l3 exactly
    }
    if (tid < 16) {
        int m = tid;
        float a0 = (m & 1) ? hw0 : 0.0f;
        float a1 = (m & 2) ? hw1 : 0.0f;
        float a2 = (m & 4) ? hw2 : 0.0f;
        float a3 = (m & 8) ? hw3 : 0.0f;
        ht_tab[tid] = ((a0 + a1) + a2) + a3;
    }

    int hb[7];         // 4-bit history: bit d == hist[j][d]; ages via >>1, spike at bit 3
    int gbase[7];      // g_tab row base (clamped for inactive j; hb stays 0 -> g == +0.0)
    float xfv[7], cnt[7];

#pragma unroll
    for (int j = 0; j < 7; j++) {
        cnt[j] = 0.f;
        hb[j] = 0;
        int n = n0 + j;
        int nc = (n < NEUR) ? n : (NEUR - 1);
        gbase[j] = nc * 16;
        if (j < cntn) {
            xfv[j] = xf_part[b * 64 + n] + xf_part[BATCH * 64 + b * 64 + n] +
                     xf_part[2 * BATCH * 64 + b * 64 + n] +
                     xf_part[3 * BATCH * 64 + b * 64 + n] + fc_b[n];
        } else {
            xfv[j] = 0.f;
        }
    }

    int wid = tid >> 6;  // 16 waves
    int lane = tid & 63;

    __syncthreads();  // tables ready

    for (int s = 0; s < STEPS; s++) {
        float g[7];
        float btl = 0.f;
#pragma unroll
        for (int j = 0; j < 7; j++) {
            g[j] = g_tab[gbase[j] + hb[j]];  // == hsum[j] bit-exactly (0.0 for inactive)
            btl += g[j];
        }
#pragma unroll
        for (int off = 4; off > 0; off >>= 1) btl += __shfl_xor(btl, off, 8);
        float rate[7];
        float lsum = 0.f;
#pragma unroll
        for (int j = 0; j < 7; j++) {
            if (j < cntn) {
                float cur = (xfv[j] + (btl - g[j])) + ht_tab[hb[j]];  // R6 expr order
                rate[j] = __expf(cur);
                lsum += rate[j];
            }
        }
#pragma unroll
        for (int off = 32; off > 0; off >>= 1) lsum += __shfl_xor(lsum, off, 64);
        if (lane == 0) red[s & 1][wid] = lsum;
        __syncthreads();
        const float4* r4 = (const float4*)red[s & 1];
        float4 q0 = r4[0], q1 = r4[1], q2 = r4[2], q3 = r4[3];
        float tsum = ((q0.x + q0.y) + (q0.z + q0.w)) + ((q1.x + q1.y) + (q1.z + q1.w)) +
                     ((q2.x + q2.y) + (q2.z + q2.w)) + ((q3.x + q3.y) + (q3.z + q3.w));
        float thr = tsum * (1.0f / (float)TOT);
#pragma unroll
        for (int j = 0; j < 7; j++) {
            if (j < cntn) {
                bool spk = rate[j] > thr;
                cnt[j] += spk ? 1.0f : 0.0f;
                hb[j] = (hb[j] >> 1) | (spk ? 8 : 0);  // age lags, insert spike at d=3
            }
        }
        // next step writes red[(s+1)&1] — different buffer, no second barrier needed
    }

#pragma unroll
    for (int j = 0; j < 7; j++) {
        if (j < cntn) {
            float c = cnt[j];
            out[b * NEUR + n0 + j] = c + log1pf(expf(-c));  // cold path: keep precise
        }
    }
}

extern "C" void kernel_launch(void* const* d_in, const int* in_sizes, int n_in,
                              void* d_out, int out_size, void* d_ws, size_t ws_size,
                              hipStream_t stream) {
    const float* x = (const float*)d_in[0];
    const float* l_weight = (const float*)d_in[1];
    const float* h_weight = (const float*)d_in[2];
    const float* fc_w = (const float*)d_in[3];
    const float* fc_b = (const float*)d_in[4];
    float* out = (float*)d_out;

    float* xf_part = (float*)d_ws;  // [4][128][64] = 131,072 B

    poolfc_kernel<<<BATCH * NQ, 1024, 0, stream>>>(x, fc_w, xf_part);
    recurrence_kernel<<<1, RTPB, 0, stream>>>(xf_part, fc_b, l_weight, h_weight, out);
}